// Round 1
// baseline (78.494 us; speedup 1.0000x reference)
//
#include <hip/hip_runtime.h>

// Log-signature depth 3, d=8, L=256, B=2048 — single fused kernel.
// One block (4 waves) per batch element. Time split into 4 chunks of 64
// steps; each wave scans its chunk from zero state (step t=255 is a Chen
// identity step). Chunk signatures are folded left-to-right by wave 0:
//   C1 = A1+B1;  C2 = A2+B2+A1⊗B1;  C3 = A3+B3+A1⊗B2+A2⊗B1.
// Lane l = (i=l>>3, j=l&7); per-lane state s1=S1[i], s2=S2[i][j],
// s3[k]=S3[i][j][k]. Per scan step (old state on RHS):
//   S3[i][j][k] += (S2[i][j] + (0.5*S1[i] + dx[i]/6)*dx[j]) * dx[k]
//   S2[i][j]    += (S1[i] + 0.5*dx[i]) * dx[j]
//   S1[i]       += dx[i]
//
// V2 (LDS-pipe relief): the old inner loop fetched the wave-uniform dx row
// via 2 broadcast ds_read_b128 per step — broadcasts pay full LDS return
// bandwidth (~24 cyc/step), making the kernel LDS-pipe bound (~30us).
// Now the row comes from the SMEM pipe: s_load of x rows (uniform address
// via readfirstlane), and dx_k is folded into split +/- FMAs with SGPR
// operands:  s3[k] += w3*x(t+1)[k] - w3*x(t)[k].
// Only the two per-lane ds_read_b32 (dxi/dxj) remain on the LDS pipe.

#define LEN 256
#define DCH 8
#define NW 4
#define CHUNK (LEN / NW)      // 64 steps per wave
#define OUTSTRIDE (DCH + DCH*DCH + DCH*DCH*DCH)  // 584

typedef float f8v __attribute__((ext_vector_type(8)));

__global__ __launch_bounds__(256) void logsig_fused(const float* __restrict__ x,
                                                    float* __restrict__ out) {
    __shared__ __align__(16) float dxbuf[LEN][DCH];   // 8 KB
    __shared__ __align__(16) float sig1[NW][8];
    __shared__ __align__(16) float sig2[NW][64];
    __shared__ __align__(16) float sig3[NW][512];
    __shared__ __align__(16) float s1buf[8];
    __shared__ __align__(16) float s2buf[64];

    const int tid  = threadIdx.x;
    const int w    = tid >> 6;
    const int lane = tid & 63;
    const int i    = lane >> 3;
    const int j    = lane & 7;
    const int b    = blockIdx.x;

    // ---- Stage dx = x[t+1]-x[t] into LDS (coalesced float4) ----
    // (needed only for the per-lane dxi/dxj b32 reads now)
    const float4* x4 = (const float4*)(x + (size_t)b * (LEN * DCH));
    float4* d4 = (float4*)&dxbuf[0][0];
    for (int f = tid; f < 512; f += 256) {
        float4 dv;
        if (f < 510) {
            float4 a = x4[f];
            float4 c = x4[f + 2];
            dv.x = c.x - a.x; dv.y = c.y - a.y; dv.z = c.z - a.z; dv.w = c.w - a.w;
        } else {
            dv.x = 0.f; dv.y = 0.f; dv.z = 0.f; dv.w = 0.f;  // zero row t=255
        }
        d4[f] = dv;
    }
    __syncthreads();

    // ---- Chunk scan: 64 steps per wave ----
    float s1 = 0.f, s2 = 0.f;
    float s3[8];
#pragma unroll
    for (int k = 0; k < 8; ++k) s3[k] = 0.f;

    const float c6 = 1.f / 6.f;

    // Wave-uniform chunk base row (readfirstlane => SGPR => scalar loads).
    const int cb = __builtin_amdgcn_readfirstlane(w) * CHUNK;
    const float* xrow = x + (size_t)b * (LEN * DCH);

    // Scalar row ping-pong: xp = x[row cb] in SGPRs.
    f8v xp = *(const f8v*)(xrow + cb * DCH);

    // Per-lane LDS base pointers; loop offsets become immediates.
    const float* di = &dxbuf[cb][i];
    const float* dj = &dxbuf[cb][j];

    for (int tb = 0; tb < CHUNK; tb += 4) {
#pragma unroll
        for (int u = 0; u < 4; ++u) {
            const int t = tb + u;
            int r = cb + t + 1;
            if (r > LEN - 1) r = LEN - 1;          // Chen identity step (dx=0)
            const f8v xc = *(const f8v*)(xrow + r * DCH);  // s_load_dwordx8
            const float dxi = di[t * DCH];          // ds_read_b32 (8-way bcast)
            const float dxj = dj[t * DCH];
            const float tt = fmaf(c6, dxi, 0.5f * s1);
            const float w3 = fmaf(tt, dxj, s2);
#pragma unroll
            for (int k = 0; k < 8; ++k) s3[k] = fmaf(w3, xc[k], s3[k]);
#pragma unroll
            for (int k = 0; k < 8; ++k) s3[k] = fmaf(-w3, xp[k], s3[k]);
            const float uu = fmaf(0.5f, dxi, s1);
            s2 = fmaf(uu, dxj, s2);
            s1 += dxi;
            xp = xc;                                // SALU s_mov ping-pong
        }
    }

    // ---- Publish chunk signatures ----
    if (j == 0) sig1[w][i] = s1;
    sig2[w][lane] = s2;
    float* sp = &sig3[w][lane * 8];
    *(float4*)(sp)     = make_float4(s3[0], s3[1], s3[2], s3[3]);
    *(float4*)(sp + 4) = make_float4(s3[4], s3[5], s3[6], s3[7]);
    __syncthreads();

    if (w != 0) return;

    // ---- Fold chunks 1..3 into wave 0's registers (A=accum, B=chunk c) ----
    for (int c = 1; c < NW; ++c) {
        float B1i  = sig1[c][i];
        float B1j  = sig1[c][j];
        float B2ij = sig2[c][lane];
        float4 b1a = *(const float4*)&sig1[c][0];
        float4 b1b = *(const float4*)&sig1[c][4];
        const float* b2row = &sig2[c][j * 8];
        float4 b2a = *(const float4*)(b2row);
        float4 b2b = *(const float4*)(b2row + 4);
        const float* b3row = &sig3[c][lane * 8];
        float4 b3a = *(const float4*)(b3row);
        float4 b3b = *(const float4*)(b3row + 4);
        float B1k[8]  = {b1a.x, b1a.y, b1a.z, b1a.w, b1b.x, b1b.y, b1b.z, b1b.w};
        float B2jk[8] = {b2a.x, b2a.y, b2a.z, b2a.w, b2b.x, b2b.y, b2b.z, b2b.w};
        float B3[8]   = {b3a.x, b3a.y, b3a.z, b3a.w, b3b.x, b3b.y, b3b.z, b3b.w};
#pragma unroll
        for (int k = 0; k < 8; ++k)   // uses OLD s1 (A1), OLD s2 (A2)
            s3[k] = s3[k] + B3[k] + s1 * B2jk[k] + s2 * B1k[k];
        s2 = s2 + B2ij + s1 * B1j;    // uses OLD s1
        s1 = s1 + B1i;
    }

    // ---- Log map epilogue (wave-internal LDS exchange) ----
    if (j == 0) s1buf[i] = s1;
    s2buf[lane] = s2;

    float S1r[8], S2rj[8];
#pragma unroll
    for (int k = 0; k < 8; ++k) S1r[k] = s1buf[k];
#pragma unroll
    for (int k = 0; k < 8; ++k) S2rj[k] = s2buf[j * 8 + k];
    float s1j = s1buf[j];

    float* ob = out + (size_t)b * OUTSTRIDE;
    if (lane < 8) ob[lane] = s1buf[lane];            // l1
    ob[8 + lane] = fmaf(-0.5f * s1, s1j, s2);        // l2

    float c3 = (1.f / 3.f) * s1 * s1j;
    float l3[8];
#pragma unroll
    for (int k = 0; k < 8; ++k)
        l3[k] = s3[k] - 0.5f * (s1 * S2rj[k] + s2 * S1r[k]) + c3 * S1r[k];
    float* p3 = ob + 72 + lane * 8;
    *(float4*)(p3)     = make_float4(l3[0], l3[1], l3[2], l3[3]);
    *(float4*)(p3 + 4) = make_float4(l3[4], l3[5], l3[6], l3[7]);
}

extern "C" void kernel_launch(void* const* d_in, const int* in_sizes, int n_in,
                              void* d_out, int out_size, void* d_ws, size_t ws_size,
                              hipStream_t stream) {
    const float* x = (const float*)d_in[0];
    float* out = (float*)d_out;
    const int B = in_sizes[0] / (LEN * DCH);   // 2048
    hipLaunchKernelGGL(logsig_fused, dim3(B), dim3(256), 0, stream, x, out);
}